// Round 1
// baseline (165.096 us; speedup 1.0000x reference)
//
#include <hip/hip_runtime.h>

// Problem constants (from reference): z(8,128,64,64) f32, codes(16,256,8) f32
// outputs: soft (8,64,64,128) f32, hard (8,64,64,128) f32, idx (8,64,64,16) int->f32
#define NPOS 32768   // B*W*H = 8*64*64
#define CCH  128
#define LL   16
#define KK   256
#define CD   8

__global__ __launch_bounds__(1024) void soft_hard_enc(
    const float* __restrict__ z, const float* __restrict__ codes,
    float* __restrict__ out)
{
    // LDS staging for transposed (channel-fastest) output writes
    __shared__ float s_soft[64][132];  // 64 pos rows x 128 ch, +4 pad (16B-aligned rows)
    __shared__ int   s_idx[64][17];    // 64 pos rows x 16 latents, +1 pad

    const int tid = (int)threadIdx.x;
    const int p   = tid & 63;                                   // position within block
    const int l   = __builtin_amdgcn_readfirstlane(tid >> 6);   // wave-uniform latent
    const int posBase = (int)blockIdx.x * 64;
    const int pos = posBase + p;
    const int b   = pos >> 12;        // / 4096
    const int wh  = pos & 4095;

    // z[b][c][w][h] with c = l*8 + cd : coalesced across lanes (consecutive wh)
    const float* zp = z + (((size_t)(b * CCH + l * CD)) << 12) + wh;
    float hv[CD];
#pragma unroll
    for (int c = 0; c < CD; ++c) hv[c] = zp[((size_t)c) << 12];

    const float* __restrict__ cp = codes + (size_t)l * KK * CD; // uniform -> s_load

    float acc[CD];
#pragma unroll
    for (int c = 0; c < CD; ++c) acc[c] = 0.0f;
    float ssum  = 0.0f;
    float bestd = 3.4e38f;
    int   bestk = 0;

#pragma unroll 4
    for (int k = 0; k < KK; ++k) {
        float cod[CD];
#pragma unroll
        for (int c = 0; c < CD; ++c) cod[c] = cp[k * CD + c];
        // direct squared distance: non-negative, no cancellation
        float d2 = 0.0f;
#pragma unroll
        for (int c = 0; c < CD; ++c) {
            float t = hv[c] - cod[c];
            d2 = fmaf(t, t, d2);
        }
        float dist = __builtin_amdgcn_sqrtf(d2);
        // softmax(-dist) without max-shift: dist>=0 so exp(-dist)<=1, no overflow
        float e = __expf(-dist);
        ssum += e;
#pragma unroll
        for (int c = 0; c < CD; ++c) acc[c] = fmaf(e, cod[c], acc[c]);
        // argmin on d2 (monotone with dist); strict < keeps first index like np.argmin
        if (d2 < bestd) { bestd = d2; bestk = k; }
    }

    const float inv = 1.0f / ssum;   // precise division, once
#pragma unroll
    for (int c = 0; c < CD; ++c) s_soft[p][l * CD + c] = acc[c] * inv;
    s_idx[p][l] = bestk;
    __syncthreads();

    // ---- output phase: thread -> (row p2, latent-chunk l2); coalesced float4 writes
    const int p2 = tid >> 4;   // 0..63
    const int l2 = tid & 15;   // 0..15
    const size_t obase = ((size_t)(posBase + p2)) * CCH + (size_t)(l2 * CD);

    float4 v0 = *(const float4*)&s_soft[p2][l2 * CD];
    float4 v1 = *(const float4*)&s_soft[p2][l2 * CD + 4];
    *(float4*)&out[obase]     = v0;
    *(float4*)&out[obase + 4] = v1;

    const int kb = s_idx[p2][l2];
    const float* hp = codes + ((size_t)(l2 * KK + kb)) * CD;   // L1/L2-resident gather
    float4 h0 = *(const float4*)&hp[0];
    float4 h1 = *(const float4*)&hp[4];
    float* outh = out + (size_t)NPOS * CCH;
    *(float4*)&outh[obase]     = h0;
    *(float4*)&outh[obase + 4] = h1;

    // idx as float, fully coalesced: offset = posBase*16 + tid
    float* outi = out + (size_t)2 * NPOS * CCH;
    outi[(size_t)posBase * LL + tid] = (float)s_idx[tid >> 4][tid & 15];
}

extern "C" void kernel_launch(void* const* d_in, const int* in_sizes, int n_in,
                              void* d_out, int out_size, void* d_ws, size_t ws_size,
                              hipStream_t stream) {
    const float* z     = (const float*)d_in[0];
    const float* codes = (const float*)d_in[1];
    float* out = (float*)d_out;
    soft_hard_enc<<<dim3(NPOS / 64), dim3(1024), 0, stream>>>(z, codes, out);
}